// Round 7
// baseline (369.944 us; speedup 1.0000x reference)
//
#include <hip/hip_runtime.h>
#include <hip/hip_bf16.h>
#include <stdint.h>

#define BB 8
#define NN 2048
#define DD 1024
#define HH 1024

using f32x4 = __attribute__((ext_vector_type(4))) float;
using s16x8 = __attribute__((ext_vector_type(8))) short;

__device__ __forceinline__ short f2bf(float f){
  union { float f; uint32_t u; } v; v.f = f;
  uint32_t r = (v.u + 0x7fffu + ((v.u >> 16) & 1u)) >> 16;
  return (short)r;
}
__device__ __forceinline__ float bf2f(short s){
  union { uint32_t u; float f; } v; v.u = ((uint32_t)(uint16_t)s) << 16; return v.f;
}

#define MFMA(a,b,c) __builtin_amdgcn_mfma_f32_16x16x32_bf16((a),(b),(c),0,0,0)

// async global->LDS, 16B per lane. LDS dest is wave-uniform base + lane*16.
#define GL16(gp, lp) __builtin_amdgcn_global_load_lds( \
    (const __attribute__((address_space(1))) void*)(gp), \
    (__attribute__((address_space(3))) void*)(lp), 16, 0, 0)

// counted-vmcnt + lgkm drain + barrier (T4): publishes this wave's staging state
// and retires this step's LDS reads before the next overwrite.
#define STEP_SYNC(N) do { \
    asm volatile("s_waitcnt vmcnt(" #N ") lgkmcnt(0)" ::: "memory"); \
    __builtin_amdgcn_sched_barrier(0); \
    __builtin_amdgcn_s_barrier(); } while(0)

// ---------------- kernel 0a: x fp32 -> bf16 ----------------
__global__ __launch_bounds__(256) void k_conv_x(const float* __restrict__ x,
                                                short* __restrict__ xb){
  int gid = blockIdx.x*256 + threadIdx.x;
  const float4* xv = (const float4*)x;
  float4 a = xv[(size_t)gid*2], b2 = xv[(size_t)gid*2+1];
  s16x8 o;
  o[0]=f2bf(a.x);  o[1]=f2bf(a.y);  o[2]=f2bf(a.z);  o[3]=f2bf(a.w);
  o[4]=f2bf(b2.x); o[5]=f2bf(b2.y); o[6]=f2bf(b2.z); o[7]=f2bf(b2.w);
  *(s16x8*)(xb + (size_t)gid*8) = o;
}

// ---------------- kernel 0b: pack W^T bf16 [3072][1024] ----------------
__global__ __launch_bounds__(256) void k_conv_w(const float* __restrict__ Wq,
                                                const float* __restrict__ Wk,
                                                const float* __restrict__ Wv,
                                                short* __restrict__ Wt){
  __shared__ float tile[64][65];
  int bx = blockIdx.x; int mat = bx >> 8; int ti = bx & 255;
  int d0 = (ti >> 4) << 6, h0 = (ti & 15) << 6;
  const float* W = (mat==0) ? Wq : (mat==1 ? Wk : Wv);
  int t = threadIdx.x;
  for (int i=0;i<16;i++){ int e = i*256 + t; int r = e>>6, c = e&63;
    tile[r][c] = W[(size_t)(d0+r)*HH + h0 + c]; }
  __syncthreads();
  for (int i=0;i<16;i++){ int e = i*256 + t; int r = e>>6, c = e&63;
    Wt[(size_t)(mat*HH + h0 + r)*DD + d0 + c] = f2bf(tile[c][r]); }
}

// ---------------- kernel 1: QKV GEMM, 4-slot BK=32 rolling pipeline ------------
// C[16384 x 3072] = xb * Wt^T (+bias). BM=BN=256, 8 waves (2Mx4N).
// 4 LDS slots/matrix (256x32 each) = 128 KiB; stage kt+3 while computing kt;
// steady-state s_waitcnt vmcnt(8) (never 0 until tail); ONE barrier per K-step.
// 16B-chunk swizzle: phys chunk = want ^ ((row>>1)&3), both-sides (rule #21).
// Operand-swap MFMA(Wfrag, xfrag): out-cols land in regs -> short4 stores.
__global__ __launch_bounds__(512,2) void k_gemm(const short* __restrict__ Aw,
                                                const short* __restrict__ Bw,
                                                const float* __restrict__ bq,
                                                const float* __restrict__ bk,
                                                const float* __restrict__ bv,
                                                short* __restrict__ Qw,
                                                short* __restrict__ Kw,
                                                short* __restrict__ Vw){
  __shared__ short Al[4][256*32];
  __shared__ short Bl[4][256*32];
  const int t = threadIdx.x, l = t & 63, w = t >> 6;
  const int g = l >> 4, c = l & 15;
  const int bn = blockIdx.x, bm = blockIdx.y;
  const int m0 = bm << 8, c0 = bn << 8;
  const int wr = w >> 2, wc = w & 3;
  f32x4 acc[8][4] = {};

  // staging: wave w owns rows w*32..w*32+31 of A and B (2 GL16 each, 4/step)
  const int srow0 = w*32 + (l >> 2), srow1 = srow0 + 16;
  const int su0 = (l & 3) ^ ((srow0 >> 1) & 3);
  const int su1 = (l & 3) ^ ((srow1 >> 1) & 3);
  const short* As0 = Aw + (size_t)(m0 + srow0)*DD + su0*8;
  const short* As1 = Aw + (size_t)(m0 + srow1)*DD + su1*8;
  const short* Bs0 = Bw + (size_t)(c0 + srow0)*DD + su0*8;
  const short* Bs1 = Bw + (size_t)(c0 + srow1)*DD + su1*8;
  auto stage = [&](int kt){
    int s = kt & 3, ko = kt*32;
    GL16(As0 + ko, (char*)&Al[s][(w*32)*32]);
    GL16(As1 + ko, (char*)&Al[s][(w*32+16)*32]);
    GL16(Bs0 + ko, (char*)&Bl[s][(w*32)*32]);
    GL16(Bs1 + ko, (char*)&Bl[s][(w*32+16)*32]);
  };

  const int rchunk = (g ^ ((c>>1)&3)) * 8;     // lane-const read swizzle
  int aoff[8], boff[4];
  #pragma unroll
  for (int mi=0;mi<8;mi++) aoff[mi] = (wr*128 + mi*16 + c)*32 + rchunk;
  #pragma unroll
  for (int ni=0;ni<4;ni++) boff[ni] = (wc*64 + ni*16 + c)*32 + rchunk;

  stage(0); stage(1); stage(2);
  STEP_SYNC(8);
  for (int kt = 0; kt < 32; ++kt){
    const int s = kt & 3;
    if (kt < 29) stage(kt+3);
    s16x8 af[8], bfr[4];
    #pragma unroll
    for (int mi=0;mi<8;mi++) af[mi] = *(const s16x8*)&Al[s][aoff[mi]];
    #pragma unroll
    for (int ni=0;ni<4;ni++) bfr[ni] = *(const s16x8*)&Bl[s][boff[ni]];
    __builtin_amdgcn_s_setprio(1);
    #pragma unroll
    for (int mi=0;mi<8;mi++)
      #pragma unroll
      for (int ni=0;ni<4;ni++)
        acc[mi][ni] = MFMA(bfr[ni], af[mi], acc[mi][ni]);
    __builtin_amdgcn_s_setprio(0);
    if (kt < 29)      STEP_SYNC(8);
    else if (kt==29)  STEP_SYNC(4);
    else if (kt==30)  STEP_SYNC(0);
  }

  // epilogue: regs span out-cols -> short4 stores, float4 bias
  const int mat = bn >> 2;
  short* Outp = (mat==0) ? Qw : (mat==1 ? Kw : Vw);
  const float* bias = (mat==0) ? bq : (mat==1 ? bk : bv);
  #pragma unroll
  for (int ni=0;ni<4;ni++){
    int col0 = (bn & 3)*256 + wc*64 + ni*16 + g*4;
    float4 bv4 = *(const float4*)&bias[col0];
    #pragma unroll
    for (int mi=0;mi<8;mi++){
      int orow = m0 + wr*128 + mi*16 + c;
      short4 pk;
      pk.x = f2bf(acc[mi][ni][0] + bv4.x);
      pk.y = f2bf(acc[mi][ni][1] + bv4.y);
      pk.z = f2bf(acc[mi][ni][2] + bv4.z);
      pk.w = f2bf(acc[mi][ni][3] + bv4.w);
      *(short4*)&Outp[(size_t)orow*HH + col0] = pk;
    }
  }
}

// ---------------- kernel 1b: V [b][n][h] -> Vt [b][h][n] ----------------
__global__ __launch_bounds__(256) void k_vtrans(const short* __restrict__ Vw,
                                                short* __restrict__ Vt){
  __shared__ uint16_t tile[64][65];
  int bx = blockIdx.x; int b = bx >> 9; int rem = bx & 511;
  int n0 = (rem >> 4) << 6, h0 = (rem & 15) << 6;
  int t = threadIdx.x;
  const uint16_t* vin = (const uint16_t*)Vw;
  uint16_t* vout = (uint16_t*)Vt;
  for (int i=0;i<16;i++){ int e = i*256 + t; int r = e>>6, c = e&63;
    tile[r][c] = vin[((size_t)b*NN + n0 + r)*HH + h0 + c]; }
  __syncthreads();
  for (int i=0;i<16;i++){ int e = i*256 + t; int r = e>>6, c = e&63;
    vout[((size_t)b*HH + h0 + r)*NN + n0 + c] = tile[c][r]; }
}

// ---------------- kernel 2: P = exp2(Q K^T * scale*log2e), causal tiles --------
// 128x128 lower-triangle tiles, 4 waves, same 4-slot pipeline (64 KiB -> 2 blk/CU).
// Operand-swap MFMA(Kfrag, Qfrag): P-cols in regs -> short4 stores to packed P.
__global__ __launch_bounds__(256,2) void k_s(const short* __restrict__ Qw,
                                             const short* __restrict__ Kw,
                                             short* __restrict__ Pp){
  __shared__ short Ql[4][128*32];
  __shared__ short Kl[4][128*32];
  const int t = threadIdx.x, l = t & 63, w = t >> 6;
  const int g = l >> 4, c = l & 15;
  int p = blockIdx.x; int b = p & 7; int ti = p >> 3;
  int tr = 0; while ((tr+1)*(tr+2)/2 <= ti) tr++;
  int tc = ti - tr*(tr+1)/2;
  const short* Aq = Qw + ((size_t)b*NN + tr*128)*HH;
  const short* Bk = Kw + ((size_t)b*NN + tc*128)*HH;
  const float SC_EXP = 0.04508422002783268f;   // (1/32) * log2(e)
  const int wq = w >> 1, wk = w & 1;
  f32x4 acc[4][4] = {};

  const int srow0 = w*32 + (l >> 2), srow1 = srow0 + 16;
  const int su0 = (l & 3) ^ ((srow0 >> 1) & 3);
  const int su1 = (l & 3) ^ ((srow1 >> 1) & 3);
  const short* Qs0 = Aq + (size_t)srow0*HH + su0*8;
  const short* Qs1 = Aq + (size_t)srow1*HH + su1*8;
  const short* Ks0 = Bk + (size_t)srow0*HH + su0*8;
  const short* Ks1 = Bk + (size_t)srow1*HH + su1*8;
  auto stage = [&](int kt){
    int s = kt & 3, ko = kt*32;
    GL16(Qs0 + ko, (char*)&Ql[s][(w*32)*32]);
    GL16(Qs1 + ko, (char*)&Ql[s][(w*32+16)*32]);
    GL16(Ks0 + ko, (char*)&Kl[s][(w*32)*32]);
    GL16(Ks1 + ko, (char*)&Kl[s][(w*32+16)*32]);
  };
  const int rchunk = (g ^ ((c>>1)&3)) * 8;
  int qoff[4], koff[4];
  #pragma unroll
  for (int mi=0;mi<4;mi++) qoff[mi] = (wq*64 + mi*16 + c)*32 + rchunk;
  #pragma unroll
  for (int ni=0;ni<4;ni++) koff[ni] = (wk*64 + ni*16 + c)*32 + rchunk;

  stage(0); stage(1); stage(2);
  STEP_SYNC(8);
  for (int kt = 0; kt < 32; ++kt){
    const int s = kt & 3;
    if (kt < 29) stage(kt+3);
    s16x8 qf[4], kf[4];
    #pragma unroll
    for (int mi=0;mi<4;mi++) qf[mi] = *(const s16x8*)&Ql[s][qoff[mi]];
    #pragma unroll
    for (int ni=0;ni<4;ni++) kf[ni] = *(const s16x8*)&Kl[s][koff[ni]];
    __builtin_amdgcn_s_setprio(1);
    #pragma unroll
    for (int mi=0;mi<4;mi++)
      #pragma unroll
      for (int ni=0;ni<4;ni++)
        acc[mi][ni] = MFMA(kf[ni], qf[mi], acc[mi][ni]);
    __builtin_amdgcn_s_setprio(0);
    if (kt < 29)      STEP_SYNC(8);
    else if (kt==29)  STEP_SYNC(4);
    else if (kt==30)  STEP_SYNC(0);
  }

  short* Pt = Pp + ((size_t)b*136 + ti)*16384;
  #pragma unroll
  for (int ni=0;ni<4;ni++){
    int pc0 = wk*64 + ni*16 + g*4;
    #pragma unroll
    for (int mi=0;mi<4;mi++){
      int pr = wq*64 + mi*16 + c;
      short4 pk;
      #pragma unroll
      for (int i=0;i<4;i++){
        bool keep = (tc*128 + pc0 + i) <= (tr*128 + pr);
        float pv = keep ? exp2f(acc[mi][ni][i]*SC_EXP) : 0.f;
        ((short*)&pk)[i] = f2bf(pv);
      }
      *(short4*)&Pt[pr*128 + pc0] = pk;
    }
  }
}

// ---------------- kernel 3: O = (P V) / rowsum(P), causal K-extent -------------
// Grid 1024, tr = p&15 so resident blocks mix short/long extents.
// Operand-swap MFMA(Vfrag, Pfrag): h-cols in regs -> float4 stores; row
// denominators recomputed in-register from P fragments (deterministic).
__global__ __launch_bounds__(256,2) void k_pv(const short* __restrict__ Pp,
                                              const short* __restrict__ Vt,
                                              float* __restrict__ out){
  __shared__ short Pl[4][128*32];
  __shared__ short Vl[4][128*32];
  const int t = threadIdx.x, l = t & 63, w = t >> 6;
  const int g = l >> 4, c = l & 15;
  int p = blockIdx.x; int tr = p & 15, b = (p >> 4) & 7, hc = p >> 7;
  const short* Pb = Pp + ((size_t)b*136 + tr*(tr+1)/2)*16384;  // tile (tr,0)
  const short* Bv = Vt + ((size_t)b*HH + hc*128)*NN;
  const int wp = w >> 1, wh = w & 1;
  f32x4 acc[4][4] = {};
  float ls[4] = {0.f,0.f,0.f,0.f};

  const int srow0 = w*32 + (l >> 2), srow1 = srow0 + 16;
  const int su0 = (l & 3) ^ ((srow0 >> 1) & 3);
  const int su1 = (l & 3) ^ ((srow1 >> 1) & 3);
  auto stage = [&](int kt){
    int s = kt & 3;
    const short* Ps = Pb + (size_t)(kt>>2)*16384 + (kt&3)*32;
    GL16(Ps + srow0*128 + su0*8, (char*)&Pl[s][(w*32)*32]);
    GL16(Ps + srow1*128 + su1*8, (char*)&Pl[s][(w*32+16)*32]);
    GL16(Bv + (size_t)srow0*NN + kt*32 + su0*8, (char*)&Vl[s][(w*32)*32]);
    GL16(Bv + (size_t)srow1*NN + kt*32 + su1*8, (char*)&Vl[s][(w*32+16)*32]);
  };
  const int rchunk = (g ^ ((c>>1)&3)) * 8;
  int poff[4], voff[4];
  #pragma unroll
  for (int mi=0;mi<4;mi++) poff[mi] = (wp*64 + mi*16 + c)*32 + rchunk;
  #pragma unroll
  for (int ni=0;ni<4;ni++) voff[ni] = (wh*64 + ni*16 + c)*32 + rchunk;

  const int nst = (tr+1)*4;              // >= 4
  stage(0); stage(1); stage(2);
  STEP_SYNC(8);
  for (int kt = 0; kt < nst; ++kt){
    const int s = kt & 3;
    if (kt + 3 < nst) stage(kt+3);
    s16x8 pf[4], vf[4];
    #pragma unroll
    for (int mi=0;mi<4;mi++) pf[mi] = *(const s16x8*)&Pl[s][poff[mi]];
    #pragma unroll
    for (int ni=0;ni<4;ni++) vf[ni] = *(const s16x8*)&Vl[s][voff[ni]];
    #pragma unroll
    for (int mi=0;mi<4;mi++)
      #pragma unroll
      for (int e=0;e<8;e++) ls[mi] += bf2f(pf[mi][e]);   // row-sum of P
    __builtin_amdgcn_s_setprio(1);
    #pragma unroll
    for (int mi=0;mi<4;mi++)
      #pragma unroll
      for (int ni=0;ni<4;ni++)
        acc[mi][ni] = MFMA(vf[ni], pf[mi], acc[mi][ni]);
    __builtin_amdgcn_s_setprio(0);
    int rem = nst - 1 - kt;
    if (rem >= 3)       STEP_SYNC(8);
    else if (rem == 2)  STEP_SYNC(4);
    else if (rem == 1)  STEP_SYNC(0);
  }
  #pragma unroll
  for (int mi=0;mi<4;mi++){
    ls[mi] += __shfl_xor(ls[mi], 16);
    ls[mi] += __shfl_xor(ls[mi], 32);    // full row-sum, lane row = wp*64+mi*16+c
  }
  #pragma unroll
  for (int mi=0;mi<4;mi++){
    float linv = 1.0f / ls[mi];
    int orow = tr*128 + wp*64 + mi*16 + c;
    #pragma unroll
    for (int ni=0;ni<4;ni++){
      int h0 = hc*128 + wh*64 + ni*16 + g*4;
      float4 o4;
      o4.x = acc[mi][ni][0]*linv; o4.y = acc[mi][ni][1]*linv;
      o4.z = acc[mi][ni][2]*linv; o4.w = acc[mi][ni][3]*linv;
      *(float4*)&out[((size_t)(b*NN + orow))*HH + h0] = o4;
    }
  }
}

extern "C" void kernel_launch(void* const* d_in, const int* in_sizes, int n_in,
                              void* d_out, int out_size, void* d_ws, size_t ws_size,
                              hipStream_t stream) {
  const float* x  = (const float*)d_in[0];
  const float* Wq = (const float*)d_in[1];
  const float* bq = (const float*)d_in[2];
  const float* Wk = (const float*)d_in[3];
  const float* bk = (const float*)d_in[4];
  const float* Wv = (const float*)d_in[5];
  const float* bv = (const float*)d_in[6];
  char* ws = (char*)d_ws;
  // ws layout (bytes). Pp (35.65 MB) OVERLAYS xb (dead after k_gemm).
  short* xb = (short*)(ws);                         // 33,554,432
  short* Pp = (short*)(ws);                         // 35,651,584 (overlay)
  short* Wt = (short*)(ws + 35651584u);             //  6,291,456
  short* Qw = (short*)(ws + 41943040u);             // 33,554,432
  short* Kw = (short*)(ws + 75497472u);             // 33,554,432
  short* Vw = (short*)(ws + 109051904u);            // 33,554,432
  short* Vt = (short*)(ws + 142606336u);            // 33,554,432

  k_conv_x<<<8192, 256, 0, stream>>>(x, xb);
  k_conv_w<<<768, 256, 0, stream>>>(Wq, Wk, Wv, Wt);
  k_gemm<<<dim3(12,64), 512, 0, stream>>>(xb, Wt, bq, bk, bv, Qw, Kw, Vw);
  k_vtrans<<<4096, 256, 0, stream>>>(Vw, Vt);
  k_s<<<1088, 256, 0, stream>>>(Qw, Kw, Pp);
  k_pv<<<1024, 256, 0, stream>>>(Pp, Vt, (float*)d_out);
}

// Round 8
// 315.391 us; speedup vs baseline: 1.1730x; 1.1730x over previous
//
#include <hip/hip_runtime.h>
#include <hip/hip_bf16.h>
#include <stdint.h>

#define BB 8
#define NN 2048
#define DD 1024
#define HH 1024

using f32x4 = __attribute__((ext_vector_type(4))) float;
using s16x8 = __attribute__((ext_vector_type(8))) short;

__device__ __forceinline__ short f2bf(float f){
  union { float f; uint32_t u; } v; v.f = f;
  uint32_t r = (v.u + 0x7fffu + ((v.u >> 16) & 1u)) >> 16;
  return (short)r;
}
__device__ __forceinline__ float bf2f(short s){
  union { uint32_t u; float f; } v; v.u = ((uint32_t)(uint16_t)s) << 16; return v.f;
}

#define MFMA(a,b,c) __builtin_amdgcn_mfma_f32_16x16x32_bf16((a),(b),(c),0,0,0)

// async global->LDS, 16B per lane. LDS dest is wave-uniform base + lane*16.
#define GL16(gp, lp) __builtin_amdgcn_global_load_lds( \
    (const __attribute__((address_space(1))) void*)(gp), \
    (__attribute__((address_space(3))) void*)(lp), 16, 0, 0)

// ---------------- kernel 0a: x fp32 -> bf16 ----------------
__global__ __launch_bounds__(256) void k_conv_x(const float* __restrict__ x,
                                                short* __restrict__ xb){
  int gid = blockIdx.x*256 + threadIdx.x;
  const float4* xv = (const float4*)x;
  float4 a = xv[(size_t)gid*2], b2 = xv[(size_t)gid*2+1];
  s16x8 o;
  o[0]=f2bf(a.x);  o[1]=f2bf(a.y);  o[2]=f2bf(a.z);  o[3]=f2bf(a.w);
  o[4]=f2bf(b2.x); o[5]=f2bf(b2.y); o[6]=f2bf(b2.z); o[7]=f2bf(b2.w);
  *(s16x8*)(xb + (size_t)gid*8) = o;
}

// ---------------- kernel 0b: pack W^T bf16 [3072][1024] ----------------
__global__ __launch_bounds__(256) void k_conv_w(const float* __restrict__ Wq,
                                                const float* __restrict__ Wk,
                                                const float* __restrict__ Wv,
                                                short* __restrict__ Wt){
  __shared__ float tile[64][65];
  int bx = blockIdx.x; int mat = bx >> 8; int ti = bx & 255;
  int d0 = (ti >> 4) << 6, h0 = (ti & 15) << 6;
  const float* W = (mat==0) ? Wq : (mat==1 ? Wk : Wv);
  int t = threadIdx.x;
  for (int i=0;i<16;i++){ int e = i*256 + t; int r = e>>6, c = e&63;
    tile[r][c] = W[(size_t)(d0+r)*HH + h0 + c]; }
  __syncthreads();
  for (int i=0;i<16;i++){ int e = i*256 + t; int r = e>>6, c = e&63;
    Wt[(size_t)(mat*HH + h0 + r)*DD + d0 + c] = f2bf(tile[c][r]); }
}

// ---------------- kernel 1: QKV GEMM, 256^2 8-phase, B-frag hoisted ------------
// C[16384 x 3072] = xb * Wt^T (+bias). BM=BN=256, BK=64, 8 waves (2Mx4N),
// 2-dbuf LDS 128 KiB, chunk^(row&7) swizzle both-sides (0 conflicts, R5-proven).
// Per tile: bfr[4][2] loaded ONCE (LDS traffic 48->24 KB/wave/tile — the R5/R6
// LDS-BW bottleneck); 8 staging GL16 issued in phases 0-1 (>=2-phase latency
// cover); per phase {af ds_reads -> barrier -> setprio 16 MFMA -> barrier};
// vmcnt(0)+barrier only at tile end (mostly pre-drained).
// XCD-aware 1D grid: bid&7 = XCD, same-XCD blocks share bm (A-panel L2 reuse).
__global__ __launch_bounds__(512,2) void k_gemm(const short* __restrict__ Aw,
                                                const short* __restrict__ Bw,
                                                const float* __restrict__ bq,
                                                const float* __restrict__ bk,
                                                const float* __restrict__ bv,
                                                short* __restrict__ Qw,
                                                short* __restrict__ Kw,
                                                short* __restrict__ Vw){
  __shared__ short Al[2][256*64];
  __shared__ short Bl[2][256*64];
  const int t = threadIdx.x, l = t & 63, w = t >> 6;
  const int g = l >> 4, c = l & 15;
  const int bid = blockIdx.x;
  const int bm = (bid & 7)*8 + ((bid >> 3) & 7);   // 0..63
  const int bn = bid >> 6;                          // 0..11
  const int m0 = bm << 8, c0 = bn << 8;
  const int wr = w >> 2, wc = w & 3;
  f32x4 acc[8][4] = {};

  const int srow = l >> 3, schunk = l & 7;
  auto stageA = [&](int kt, int buf, int j){
    int row = j*64 + w*8 + srow;
    int u = schunk ^ (row & 7);
    GL16(Aw + (size_t)(m0+row)*DD + kt*64 + u*8,
         ((char*)&Al[buf][0]) + (j*64 + w*8)*128);
  };
  auto stageB = [&](int kt, int buf, int j){
    int row = j*64 + w*8 + srow;
    int u = schunk ^ (row & 7);
    GL16(Bw + (size_t)(c0+row)*DD + kt*64 + u*8,
         ((char*)&Bl[buf][0]) + (j*64 + w*8)*128);
  };

  #pragma unroll
  for (int j=0;j<4;j++){ stageA(0,0,j); stageB(0,0,j); }
  __syncthreads();

  for (int kt = 0; kt < 16; ++kt){
    const int cur = kt & 1;
    const bool pf = (kt < 15);
    // B-fragments once per tile
    s16x8 bfr[4][2];
    #pragma unroll
    for (int ni=0;ni<4;ni++){
      int row = wc*64 + ni*16 + c;
      #pragma unroll
      for (int kk=0;kk<2;kk++)
        bfr[ni][kk] = *(const s16x8*)&Bl[cur][row*64 + (((kk*4+g)^(c&7))*8)];
    }
    #pragma unroll
    for (int p = 0; p < 4; ++p){
      s16x8 af[2][2];
      #pragma unroll
      for (int m2=0;m2<2;m2++){
        int row = wr*128 + (p*2+m2)*16 + c;
        #pragma unroll
        for (int kk=0;kk<2;kk++)
          af[m2][kk] = *(const s16x8*)&Al[cur][row*64 + (((kk*4+g)^(c&7))*8)];
      }
      if (pf){
        if      (p==0){ stageA(kt+1,cur^1,0); stageA(kt+1,cur^1,1);
                        stageB(kt+1,cur^1,0); stageB(kt+1,cur^1,1); }
        else if (p==1){ stageA(kt+1,cur^1,2); stageA(kt+1,cur^1,3);
                        stageB(kt+1,cur^1,2); stageB(kt+1,cur^1,3); }
      }
      __builtin_amdgcn_s_barrier();
      __builtin_amdgcn_s_setprio(1);
      #pragma unroll
      for (int m2=0;m2<2;m2++)
        #pragma unroll
        for (int ni=0;ni<4;ni++)
          #pragma unroll
          for (int kk=0;kk<2;kk++)
            acc[p*2+m2][ni] = MFMA(bfr[ni][kk], af[m2][kk], acc[p*2+m2][ni]);
      __builtin_amdgcn_s_setprio(0);
      if (p < 3) __builtin_amdgcn_s_barrier();
    }
    asm volatile("s_waitcnt vmcnt(0)" ::: "memory");
    __builtin_amdgcn_s_barrier();
  }

  // epilogue: swapped layout -> out-cols in regs -> short4 stores, float4 bias
  const int mat = bn >> 2;
  short* Outp = (mat==0) ? Qw : (mat==1 ? Kw : Vw);
  const float* bias = (mat==0) ? bq : (mat==1 ? bk : bv);
  #pragma unroll
  for (int ni=0;ni<4;ni++){
    int col0 = (bn & 3)*256 + wc*64 + ni*16 + g*4;
    float4 bv4 = *(const float4*)&bias[col0];
    #pragma unroll
    for (int mi=0;mi<8;mi++){
      int orow = m0 + wr*128 + mi*16 + c;
      short4 pk;
      pk.x = f2bf(acc[mi][ni][0] + bv4.x);
      pk.y = f2bf(acc[mi][ni][1] + bv4.y);
      pk.z = f2bf(acc[mi][ni][2] + bv4.z);
      pk.w = f2bf(acc[mi][ni][3] + bv4.w);
      *(short4*)&Outp[(size_t)orow*HH + col0] = pk;
    }
  }
}

// ---------------- kernel 1b: V [b][n][h] -> Vt [b][h][n] ----------------
__global__ __launch_bounds__(256) void k_vtrans(const short* __restrict__ Vw,
                                                short* __restrict__ Vt){
  __shared__ uint16_t tile[64][65];
  int bx = blockIdx.x; int b = bx >> 9; int rem = bx & 511;
  int n0 = (rem >> 4) << 6, h0 = (rem & 15) << 6;
  int t = threadIdx.x;
  const uint16_t* vin = (const uint16_t*)Vw;
  uint16_t* vout = (uint16_t*)Vt;
  for (int i=0;i<16;i++){ int e = i*256 + t; int r = e>>6, c = e&63;
    tile[r][c] = vin[((size_t)b*NN + n0 + r)*HH + h0 + c]; }
  __syncthreads();
  for (int i=0;i<16;i++){ int e = i*256 + t; int r = e>>6, c = e&63;
    vout[((size_t)b*HH + h0 + r)*NN + n0 + c] = tile[c][r]; }
}

// ---------------- kernel 2: P = exp2(Q K^T * scale*log2e), causal tiles --------
// 128x128 lower-triangle tiles, 4 waves, 16 KiB single-buffer 2-barrier
// (high occupancy; cross-block overlap hides latency — m114). Swizzled
// GL16-source + reads (0 conflicts); swapped MFMA(K,Q) -> short4 P stores.
__global__ __launch_bounds__(256) void k_s(const short* __restrict__ Qw,
                                           const short* __restrict__ Kw,
                                           short* __restrict__ Pp){
  __shared__ short Ql[128*32];
  __shared__ short Kl[128*32];
  const int t = threadIdx.x, l = t & 63, w = t >> 6;
  const int g = l >> 4, c = l & 15;
  int p = blockIdx.x; int b = p & 7; int ti = p >> 3;
  int tr = 0; while ((tr+1)*(tr+2)/2 <= ti) tr++;
  int tc = ti - tr*(tr+1)/2;
  const short* Aq = Qw + ((size_t)b*NN + tr*128)*HH;
  const short* Bk = Kw + ((size_t)b*NN + tc*128)*HH;
  const float SC_EXP = 0.04508422002783268f;   // (1/32) * log2(e)
  const int wq = w >> 1, wk = w & 1;
  f32x4 acc[4][4] = {};

  const int srow0 = w*32 + (l >> 2), srow1 = srow0 + 16;
  const int su0 = (l & 3) ^ ((srow0 >> 1) & 3);
  const int su1 = (l & 3) ^ ((srow1 >> 1) & 3);
  const short* Qs0 = Aq + (size_t)srow0*HH + su0*8;
  const short* Qs1 = Aq + (size_t)srow1*HH + su1*8;
  const short* Ks0 = Bk + (size_t)srow0*HH + su0*8;
  const short* Ks1 = Bk + (size_t)srow1*HH + su1*8;
  const int rchunk = (g ^ ((c>>1)&3)) * 8;
  int qoff[4], koff[4];
  #pragma unroll
  for (int mi=0;mi<4;mi++) qoff[mi] = (wq*64 + mi*16 + c)*32 + rchunk;
  #pragma unroll
  for (int ni=0;ni<4;ni++) koff[ni] = (wk*64 + ni*16 + c)*32 + rchunk;

  for (int kt = 0; kt < 32; ++kt){
    int ko = kt*32;
    __syncthreads();
    GL16(Qs0 + ko, (char*)&Ql[(w*32)*32]);
    GL16(Qs1 + ko, (char*)&Ql[(w*32+16)*32]);
    GL16(Ks0 + ko, (char*)&Kl[(w*32)*32]);
    GL16(Ks1 + ko, (char*)&Kl[(w*32+16)*32]);
    __syncthreads();
    s16x8 qf[4], kf[4];
    #pragma unroll
    for (int mi=0;mi<4;mi++) qf[mi] = *(const s16x8*)&Ql[qoff[mi]];
    #pragma unroll
    for (int ni=0;ni<4;ni++) kf[ni] = *(const s16x8*)&Kl[koff[ni]];
    #pragma unroll
    for (int mi=0;mi<4;mi++)
      #pragma unroll
      for (int ni=0;ni<4;ni++)
        acc[mi][ni] = MFMA(kf[ni], qf[mi], acc[mi][ni]);
  }

  short* Pt = Pp + ((size_t)b*136 + ti)*16384;
  #pragma unroll
  for (int ni=0;ni<4;ni++){
    int pc0 = wk*64 + ni*16 + g*4;
    #pragma unroll
    for (int mi=0;mi<4;mi++){
      int pr = wq*64 + mi*16 + c;
      short4 pk;
      #pragma unroll
      for (int i=0;i<4;i++){
        bool keep = (tc*128 + pc0 + i) <= (tr*128 + pr);
        float pv = keep ? exp2f(acc[mi][ni][i]*SC_EXP) : 0.f;
        ((short*)&pk)[i] = f2bf(pv);
      }
      *(short4*)&Pt[pr*128 + pc0] = pk;
    }
  }
}

// ---------------- kernel 3: O = (P V) / rowsum(P), causal K-extent -------------
// Same 16 KiB 2-barrier structure. tr = p&15 mixes short/long extents.
// Swapped MFMA(V,P): h-cols in regs -> float4 stores; denominators in-register.
__global__ __launch_bounds__(256) void k_pv(const short* __restrict__ Pp,
                                            const short* __restrict__ Vt,
                                            float* __restrict__ out){
  __shared__ short Pl[128*32];
  __shared__ short Vl[128*32];
  const int t = threadIdx.x, l = t & 63, w = t >> 6;
  const int g = l >> 4, c = l & 15;
  int p = blockIdx.x; int tr = p & 15, b = (p >> 4) & 7, hc = p >> 7;
  const short* Pb = Pp + ((size_t)b*136 + tr*(tr+1)/2)*16384;  // tile (tr,0)
  const short* Bv = Vt + ((size_t)b*HH + hc*128)*NN;
  const int wp = w >> 1, wh = w & 1;
  f32x4 acc[4][4] = {};
  float ls[4] = {0.f,0.f,0.f,0.f};

  const int srow0 = w*32 + (l >> 2), srow1 = srow0 + 16;
  const int su0 = (l & 3) ^ ((srow0 >> 1) & 3);
  const int su1 = (l & 3) ^ ((srow1 >> 1) & 3);
  const int rchunk = (g ^ ((c>>1)&3)) * 8;
  int poff[4], voff[4];
  #pragma unroll
  for (int mi=0;mi<4;mi++) poff[mi] = (wp*64 + mi*16 + c)*32 + rchunk;
  #pragma unroll
  for (int ni=0;ni<4;ni++) voff[ni] = (wh*64 + ni*16 + c)*32 + rchunk;

  const int nst = (tr+1)*4;
  for (int kt = 0; kt < nst; ++kt){
    const short* Ps = Pb + (size_t)(kt>>2)*16384 + (kt&3)*32;
    __syncthreads();
    GL16(Ps + srow0*128 + su0*8, (char*)&Pl[(w*32)*32]);
    GL16(Ps + srow1*128 + su1*8, (char*)&Pl[(w*32+16)*32]);
    GL16(Bv + (size_t)srow0*NN + kt*32 + su0*8, (char*)&Vl[(w*32)*32]);
    GL16(Bv + (size_t)srow1*NN + kt*32 + su1*8, (char*)&Vl[(w*32+16)*32]);
    __syncthreads();
    s16x8 pf[4], vf[4];
    #pragma unroll
    for (int mi=0;mi<4;mi++) pf[mi] = *(const s16x8*)&Pl[poff[mi]];
    #pragma unroll
    for (int ni=0;ni<4;ni++) vf[ni] = *(const s16x8*)&Vl[voff[ni]];
    #pragma unroll
    for (int mi=0;mi<4;mi++)
      #pragma unroll
      for (int e=0;e<8;e++) ls[mi] += bf2f(pf[mi][e]);   // row-sum of P
    #pragma unroll
    for (int mi=0;mi<4;mi++)
      #pragma unroll
      for (int ni=0;ni<4;ni++)
        acc[mi][ni] = MFMA(vf[ni], pf[mi], acc[mi][ni]);
  }
  #pragma unroll
  for (int mi=0;mi<4;mi++){
    ls[mi] += __shfl_xor(ls[mi], 16);
    ls[mi] += __shfl_xor(ls[mi], 32);    // full row-sum; lane row = wp*64+mi*16+c
  }
  #pragma unroll
  for (int mi=0;mi<4;mi++){
    float linv = 1.0f / ls[mi];
    int orow = tr*128 + wp*64 + mi*16 + c;
    #pragma unroll
    for (int ni=0;ni<4;ni++){
      int h0 = hc*128 + wh*64 + ni*16 + g*4;
      float4 o4;
      o4.x = acc[mi][ni][0]*linv; o4.y = acc[mi][ni][1]*linv;
      o4.z = acc[mi][ni][2]*linv; o4.w = acc[mi][ni][3]*linv;
      *(float4*)&out[((size_t)(b*NN + orow))*HH + h0] = o4;
    }
  }
}

extern "C" void kernel_launch(void* const* d_in, const int* in_sizes, int n_in,
                              void* d_out, int out_size, void* d_ws, size_t ws_size,
                              hipStream_t stream) {
  const float* x  = (const float*)d_in[0];
  const float* Wq = (const float*)d_in[1];
  const float* bq = (const float*)d_in[2];
  const float* Wk = (const float*)d_in[3];
  const float* bk = (const float*)d_in[4];
  const float* Wv = (const float*)d_in[5];
  const float* bv = (const float*)d_in[6];
  char* ws = (char*)d_ws;
  // ws layout (bytes). Pp (35.65 MB) OVERLAYS xb (dead after k_gemm).
  short* xb = (short*)(ws);                         // 33,554,432
  short* Pp = (short*)(ws);                         // 35,651,584 (overlay)
  short* Wt = (short*)(ws + 35651584u);             //  6,291,456
  short* Qw = (short*)(ws + 41943040u);             // 33,554,432
  short* Kw = (short*)(ws + 75497472u);             // 33,554,432
  short* Vw = (short*)(ws + 109051904u);            // 33,554,432
  short* Vt = (short*)(ws + 142606336u);            // 33,554,432

  k_conv_x<<<8192, 256, 0, stream>>>(x, xb);
  k_conv_w<<<768, 256, 0, stream>>>(Wq, Wk, Wv, Wt);
  k_gemm<<<768, 512, 0, stream>>>(xb, Wt, bq, bk, bv, Qw, Kw, Vw);
  k_vtrans<<<4096, 256, 0, stream>>>(Vw, Vt);
  k_s<<<1088, 256, 0, stream>>>(Qw, Kw, Pp);
  k_pv<<<1024, 256, 0, stream>>>(Pp, Vt, (float*)d_out);
}

// Round 9
// 292.313 us; speedup vs baseline: 1.2656x; 1.0790x over previous
//
#include <hip/hip_runtime.h>
#include <hip/hip_bf16.h>
#include <stdint.h>

#define BB 8
#define NN 2048
#define DD 1024
#define HH 1024

using f32x4 = __attribute__((ext_vector_type(4))) float;
using s16x8 = __attribute__((ext_vector_type(8))) short;

__device__ __forceinline__ short f2bf(float f){
  union { float f; uint32_t u; } v; v.f = f;
  uint32_t r = (v.u + 0x7fffu + ((v.u >> 16) & 1u)) >> 16;
  return (short)r;
}
__device__ __forceinline__ float bf2f(short s){
  union { uint32_t u; float f; } v; v.u = ((uint32_t)(uint16_t)s) << 16; return v.f;
}

#define MFMA(a,b,c) __builtin_amdgcn_mfma_f32_16x16x32_bf16((a),(b),(c),0,0,0)

// async global->LDS, 16B per lane. LDS dest is wave-uniform base + lane*16.
#define GL16(gp, lp) __builtin_amdgcn_global_load_lds( \
    (const __attribute__((address_space(1))) void*)(gp), \
    (__attribute__((address_space(3))) void*)(lp), 16, 0, 0)

// ---------------- kernel 0a: x fp32 -> bf16 ----------------
__global__ __launch_bounds__(256) void k_conv_x(const float* __restrict__ x,
                                                short* __restrict__ xb){
  int gid = blockIdx.x*256 + threadIdx.x;
  const float4* xv = (const float4*)x;
  float4 a = xv[(size_t)gid*2], b2 = xv[(size_t)gid*2+1];
  s16x8 o;
  o[0]=f2bf(a.x);  o[1]=f2bf(a.y);  o[2]=f2bf(a.z);  o[3]=f2bf(a.w);
  o[4]=f2bf(b2.x); o[5]=f2bf(b2.y); o[6]=f2bf(b2.z); o[7]=f2bf(b2.w);
  *(s16x8*)(xb + (size_t)gid*8) = o;
}

// ---------------- kernel 0b: pack W^T bf16 [3072][1024] ----------------
__global__ __launch_bounds__(256) void k_conv_w(const float* __restrict__ Wq,
                                                const float* __restrict__ Wk,
                                                const float* __restrict__ Wv,
                                                short* __restrict__ Wt){
  __shared__ float tile[64][65];
  int bx = blockIdx.x; int mat = bx >> 8; int ti = bx & 255;
  int d0 = (ti >> 4) << 6, h0 = (ti & 15) << 6;
  const float* W = (mat==0) ? Wq : (mat==1 ? Wk : Wv);
  int t = threadIdx.x;
  for (int i=0;i<16;i++){ int e = i*256 + t; int r = e>>6, c = e&63;
    tile[r][c] = W[(size_t)(d0+r)*HH + h0 + c]; }
  __syncthreads();
  for (int i=0;i<16;i++){ int e = i*256 + t; int r = e>>6, c = e&63;
    Wt[(size_t)(mat*HH + h0 + r)*DD + d0 + c] = f2bf(tile[c][r]); }
}

// ---------------- kernel 1: QKV GEMM, 256^2, 2-phase/tile ----------------------
// C[16384 x 3072] = xb * Wt^T (+bias). BM=BN=256, BK=64, 8 waves (2Mx4N),
// 2-dbuf LDS 128 KiB, chunk^(row&7) swizzle both-sides (0 conflicts).
// Per tile: bfr[4][2] hoisted (read once); 2 phases x {af[4][2] reads ->
// barrier -> 32 MFMA -> barrier}; ALL 8 staging GL16 issued in phase 0
// (>=1-phase drain cover); vmcnt(0)+barrier only at tile end.
// XCD-aware 1D grid: bid&7 = XCD, same-XCD blocks share bm (A-panel L2 reuse).
__global__ __launch_bounds__(512,2) void k_gemm(const short* __restrict__ Aw,
                                                const short* __restrict__ Bw,
                                                const float* __restrict__ bq,
                                                const float* __restrict__ bk,
                                                const float* __restrict__ bv,
                                                short* __restrict__ Qw,
                                                short* __restrict__ Kw,
                                                short* __restrict__ Vw){
  __shared__ short Al[2][256*64];
  __shared__ short Bl[2][256*64];
  const int t = threadIdx.x, l = t & 63, w = t >> 6;
  const int g = l >> 4, c = l & 15;
  const int bid = blockIdx.x;
  const int bm = (bid & 7)*8 + ((bid >> 3) & 7);   // 0..63
  const int bn = bid >> 6;                          // 0..11
  const int m0 = bm << 8, c0 = bn << 8;
  const int wr = w >> 2, wc = w & 3;
  f32x4 acc[8][4] = {};

  const int srow = l >> 3, schunk = l & 7;
  auto stageA = [&](int kt, int buf, int j){
    int row = j*64 + w*8 + srow;
    int u = schunk ^ (row & 7);
    GL16(Aw + (size_t)(m0+row)*DD + kt*64 + u*8,
         ((char*)&Al[buf][0]) + (j*64 + w*8)*128);
  };
  auto stageB = [&](int kt, int buf, int j){
    int row = j*64 + w*8 + srow;
    int u = schunk ^ (row & 7);
    GL16(Bw + (size_t)(c0+row)*DD + kt*64 + u*8,
         ((char*)&Bl[buf][0]) + (j*64 + w*8)*128);
  };

  #pragma unroll
  for (int j=0;j<4;j++){ stageA(0,0,j); stageB(0,0,j); }
  __syncthreads();

  for (int kt = 0; kt < 16; ++kt){
    const int cur = kt & 1;
    // B-fragments once per tile
    s16x8 bfr[4][2];
    #pragma unroll
    for (int ni=0;ni<4;ni++){
      int row = wc*64 + ni*16 + c;
      #pragma unroll
      for (int kk=0;kk<2;kk++)
        bfr[ni][kk] = *(const s16x8*)&Bl[cur][row*64 + (((kk*4+g)^(c&7))*8)];
    }
    #pragma unroll
    for (int h = 0; h < 2; ++h){
      s16x8 af[4][2];
      #pragma unroll
      for (int m2=0;m2<4;m2++){
        int row = wr*128 + (h*4+m2)*16 + c;
        #pragma unroll
        for (int kk=0;kk<2;kk++)
          af[m2][kk] = *(const s16x8*)&Al[cur][row*64 + (((kk*4+g)^(c&7))*8)];
      }
      if (h==0 && kt < 15){
        #pragma unroll
        for (int j=0;j<4;j++){ stageA(kt+1,cur^1,j); stageB(kt+1,cur^1,j); }
      }
      __builtin_amdgcn_s_barrier();
      __builtin_amdgcn_s_setprio(1);
      #pragma unroll
      for (int m2=0;m2<4;m2++)
        #pragma unroll
        for (int ni=0;ni<4;ni++)
          #pragma unroll
          for (int kk=0;kk<2;kk++)
            acc[h*4+m2][ni] = MFMA(bfr[ni][kk], af[m2][kk], acc[h*4+m2][ni]);
      __builtin_amdgcn_s_setprio(0);
      if (h==0) __builtin_amdgcn_s_barrier();
    }
    asm volatile("s_waitcnt vmcnt(0)" ::: "memory");
    __builtin_amdgcn_sched_barrier(0);
    __builtin_amdgcn_s_barrier();
  }

  // epilogue: swapped layout -> out-cols in regs -> short4 stores, float4 bias
  const int mat = bn >> 2;
  short* Outp = (mat==0) ? Qw : (mat==1 ? Kw : Vw);
  const float* bias = (mat==0) ? bq : (mat==1 ? bk : bv);
  #pragma unroll
  for (int ni=0;ni<4;ni++){
    int col0 = (bn & 3)*256 + wc*64 + ni*16 + g*4;
    float4 bv4 = *(const float4*)&bias[col0];
    #pragma unroll
    for (int mi=0;mi<8;mi++){
      int orow = m0 + wr*128 + mi*16 + c;
      short4 pk;
      pk.x = f2bf(acc[mi][ni][0] + bv4.x);
      pk.y = f2bf(acc[mi][ni][1] + bv4.y);
      pk.z = f2bf(acc[mi][ni][2] + bv4.z);
      pk.w = f2bf(acc[mi][ni][3] + bv4.w);
      *(short4*)&Outp[(size_t)orow*HH + col0] = pk;
    }
  }
}

// ---------------- kernel 1b: V [b][n][h] -> Vt [b][h][n] ----------------
__global__ __launch_bounds__(256) void k_vtrans(const short* __restrict__ Vw,
                                                short* __restrict__ Vt){
  __shared__ uint16_t tile[64][65];
  int bx = blockIdx.x; int b = bx >> 9; int rem = bx & 511;
  int n0 = (rem >> 4) << 6, h0 = (rem & 15) << 6;
  int t = threadIdx.x;
  const uint16_t* vin = (const uint16_t*)Vw;
  uint16_t* vout = (uint16_t*)Vt;
  for (int i=0;i<16;i++){ int e = i*256 + t; int r = e>>6, c = e&63;
    tile[r][c] = vin[((size_t)b*NN + n0 + r)*HH + h0 + c]; }
  __syncthreads();
  for (int i=0;i<16;i++){ int e = i*256 + t; int r = e>>6, c = e&63;
    vout[((size_t)b*HH + h0 + r)*NN + n0 + c] = tile[c][r]; }
}

// ---------------- kernel 2: P = exp2(Q K^T * scale*log2e), causal tiles --------
// 128x128 lower-triangle tiles, 4 waves, 16 KiB single-buffer 2-barrier
// (high occupancy; cross-block overlap hides latency — m114). Swizzled
// GL16-source + reads (0 conflicts); swapped MFMA(K,Q) -> short4 P stores.
__global__ __launch_bounds__(256) void k_s(const short* __restrict__ Qw,
                                           const short* __restrict__ Kw,
                                           short* __restrict__ Pp){
  __shared__ short Ql[128*32];
  __shared__ short Kl[128*32];
  const int t = threadIdx.x, l = t & 63, w = t >> 6;
  const int g = l >> 4, c = l & 15;
  int p = blockIdx.x; int b = p & 7; int ti = p >> 3;
  int tr = 0; while ((tr+1)*(tr+2)/2 <= ti) tr++;
  int tc = ti - tr*(tr+1)/2;
  const short* Aq = Qw + ((size_t)b*NN + tr*128)*HH;
  const short* Bk = Kw + ((size_t)b*NN + tc*128)*HH;
  const float SC_EXP = 0.04508422002783268f;   // (1/32) * log2(e)
  const int wq = w >> 1, wk = w & 1;
  f32x4 acc[4][4] = {};

  const int srow0 = w*32 + (l >> 2), srow1 = srow0 + 16;
  const int su0 = (l & 3) ^ ((srow0 >> 1) & 3);
  const int su1 = (l & 3) ^ ((srow1 >> 1) & 3);
  const short* Qs0 = Aq + (size_t)srow0*HH + su0*8;
  const short* Qs1 = Aq + (size_t)srow1*HH + su1*8;
  const short* Ks0 = Bk + (size_t)srow0*HH + su0*8;
  const short* Ks1 = Bk + (size_t)srow1*HH + su1*8;
  const int rchunk = (g ^ ((c>>1)&3)) * 8;
  int qoff[4], koff[4];
  #pragma unroll
  for (int mi=0;mi<4;mi++) qoff[mi] = (wq*64 + mi*16 + c)*32 + rchunk;
  #pragma unroll
  for (int ni=0;ni<4;ni++) koff[ni] = (wk*64 + ni*16 + c)*32 + rchunk;

  for (int kt = 0; kt < 32; ++kt){
    int ko = kt*32;
    __syncthreads();
    GL16(Qs0 + ko, (char*)&Ql[(w*32)*32]);
    GL16(Qs1 + ko, (char*)&Ql[(w*32+16)*32]);
    GL16(Ks0 + ko, (char*)&Kl[(w*32)*32]);
    GL16(Ks1 + ko, (char*)&Kl[(w*32+16)*32]);
    __syncthreads();
    s16x8 qf[4], kf[4];
    #pragma unroll
    for (int mi=0;mi<4;mi++) qf[mi] = *(const s16x8*)&Ql[qoff[mi]];
    #pragma unroll
    for (int ni=0;ni<4;ni++) kf[ni] = *(const s16x8*)&Kl[koff[ni]];
    #pragma unroll
    for (int mi=0;mi<4;mi++)
      #pragma unroll
      for (int ni=0;ni<4;ni++)
        acc[mi][ni] = MFMA(kf[ni], qf[mi], acc[mi][ni]);
  }

  short* Pt = Pp + ((size_t)b*136 + ti)*16384;
  #pragma unroll
  for (int ni=0;ni<4;ni++){
    int pc0 = wk*64 + ni*16 + g*4;
    #pragma unroll
    for (int mi=0;mi<4;mi++){
      int pr = wq*64 + mi*16 + c;
      short4 pk;
      #pragma unroll
      for (int i=0;i<4;i++){
        bool keep = (tc*128 + pc0 + i) <= (tr*128 + pr);
        float pv = keep ? exp2f(acc[mi][ni][i]*SC_EXP) : 0.f;
        ((short*)&pk)[i] = f2bf(pv);
      }
      *(short4*)&Pt[pr*128 + pc0] = pk;
    }
  }
}

// ---------------- kernel 3: O = (P V) / rowsum(P), causal K-extent -------------
// PERFECTLY BALANCED grid: 4 dispatch rounds of 256; per round the 256 slots
// cover each tr exactly 16x, and rounds pair tr with 15-tr so every CU's four
// resident blocks sum to 34 step-units (= mean). Bijective (tr,id) coverage.
__global__ __launch_bounds__(256) void k_pv(const short* __restrict__ Pp,
                                            const short* __restrict__ Vt,
                                            float* __restrict__ out){
  __shared__ short Pl[128*32];
  __shared__ short Vl[128*32];
  const int t = threadIdx.x, l = t & 63, w = t >> 6;
  const int g = l >> 4, c = l & 15;
  int p = blockIdx.x;
  int r = p >> 8, j = p & 255;
  int tr, id;
  if      (r==0){ tr = j>>4;        id = (j&15); }
  else if (r==1){ tr = 15-(j>>4);   id = 16 + (j&15); }
  else if (r==2){ tr = (j&15);      id = 32 + (j>>4); }
  else          { tr = 15-(j&15);   id = 48 + (j>>4); }
  int b = id & 7, hc = id >> 3;
  const short* Pb = Pp + ((size_t)b*136 + tr*(tr+1)/2)*16384;  // tile (tr,0)
  const short* Bv = Vt + ((size_t)b*HH + hc*128)*NN;
  const int wp = w >> 1, wh = w & 1;
  f32x4 acc[4][4] = {};
  float ls[4] = {0.f,0.f,0.f,0.f};

  const int srow0 = w*32 + (l >> 2), srow1 = srow0 + 16;
  const int su0 = (l & 3) ^ ((srow0 >> 1) & 3);
  const int su1 = (l & 3) ^ ((srow1 >> 1) & 3);
  const int rchunk = (g ^ ((c>>1)&3)) * 8;
  int poff[4], voff[4];
  #pragma unroll
  for (int mi=0;mi<4;mi++) poff[mi] = (wp*64 + mi*16 + c)*32 + rchunk;
  #pragma unroll
  for (int ni=0;ni<4;ni++) voff[ni] = (wh*64 + ni*16 + c)*32 + rchunk;

  const int nst = (tr+1)*4;
  for (int kt = 0; kt < nst; ++kt){
    const short* Ps = Pb + (size_t)(kt>>2)*16384 + (kt&3)*32;
    __syncthreads();
    GL16(Ps + srow0*128 + su0*8, (char*)&Pl[(w*32)*32]);
    GL16(Ps + srow1*128 + su1*8, (char*)&Pl[(w*32+16)*32]);
    GL16(Bv + (size_t)srow0*NN + kt*32 + su0*8, (char*)&Vl[(w*32)*32]);
    GL16(Bv + (size_t)srow1*NN + kt*32 + su1*8, (char*)&Vl[(w*32+16)*32]);
    __syncthreads();
    s16x8 pf[4], vf[4];
    #pragma unroll
    for (int mi=0;mi<4;mi++) pf[mi] = *(const s16x8*)&Pl[poff[mi]];
    #pragma unroll
    for (int ni=0;ni<4;ni++) vf[ni] = *(const s16x8*)&Vl[voff[ni]];
    #pragma unroll
    for (int mi=0;mi<4;mi++)
      #pragma unroll
      for (int e=0;e<8;e++) ls[mi] += bf2f(pf[mi][e]);   // row-sum of P
    #pragma unroll
    for (int mi=0;mi<4;mi++)
      #pragma unroll
      for (int ni=0;ni<4;ni++)
        acc[mi][ni] = MFMA(vf[ni], pf[mi], acc[mi][ni]);
  }
  #pragma unroll
  for (int mi=0;mi<4;mi++){
    ls[mi] += __shfl_xor(ls[mi], 16);
    ls[mi] += __shfl_xor(ls[mi], 32);    // full row-sum; lane row = wp*64+mi*16+c
  }
  #pragma unroll
  for (int mi=0;mi<4;mi++){
    float linv = 1.0f / ls[mi];
    int orow = tr*128 + wp*64 + mi*16 + c;
    #pragma unroll
    for (int ni=0;ni<4;ni++){
      int h0 = hc*128 + wh*64 + ni*16 + g*4;
      float4 o4;
      o4.x = acc[mi][ni][0]*linv; o4.y = acc[mi][ni][1]*linv;
      o4.z = acc[mi][ni][2]*linv; o4.w = acc[mi][ni][3]*linv;
      *(float4*)&out[((size_t)(b*NN + orow))*HH + h0] = o4;
    }
  }
}

extern "C" void kernel_launch(void* const* d_in, const int* in_sizes, int n_in,
                              void* d_out, int out_size, void* d_ws, size_t ws_size,
                              hipStream_t stream) {
  const float* x  = (const float*)d_in[0];
  const float* Wq = (const float*)d_in[1];
  const float* bq = (const float*)d_in[2];
  const float* Wk = (const float*)d_in[3];
  const float* bk = (const float*)d_in[4];
  const float* Wv = (const float*)d_in[5];
  const float* bv = (const float*)d_in[6];
  char* ws = (char*)d_ws;
  // ws layout (bytes). Pp (35.65 MB) OVERLAYS xb (dead after k_gemm).
  short* xb = (short*)(ws);                         // 33,554,432
  short* Pp = (short*)(ws);                         // 35,651,584 (overlay)
  short* Wt = (short*)(ws + 35651584u);             //  6,291,456
  short* Qw = (short*)(ws + 41943040u);             // 33,554,432
  short* Kw = (short*)(ws + 75497472u);             // 33,554,432
  short* Vw = (short*)(ws + 109051904u);            // 33,554,432
  short* Vt = (short*)(ws + 142606336u);            // 33,554,432

  k_conv_x<<<8192, 256, 0, stream>>>(x, xb);
  k_conv_w<<<768, 256, 0, stream>>>(Wq, Wk, Wv, Wt);
  k_gemm<<<768, 512, 0, stream>>>(xb, Wt, bq, bk, bv, Qw, Kw, Vw);
  k_vtrans<<<4096, 256, 0, stream>>>(Vw, Vt);
  k_s<<<1088, 256, 0, stream>>>(Qw, Kw, Pp);
  k_pv<<<1024, 256, 0, stream>>>(Pp, Vt, (float*)d_out);
}